// Round 3
// baseline (346.356 us; speedup 1.0000x reference)
//
#include <hip/hip_runtime.h>
#include <stdint.h>
#include <stddef.h>

// Problem constants
#define NV    32000
#define HDIM  512
#define LSRC  320
#define MROWS 1024          // B * L_R
#define SCALEF 0.044194173824159216f   // 1/sqrt(512)

typedef unsigned short u16;
typedef unsigned int   u32;
typedef __attribute__((ext_vector_type(8))) short short8;   // 8 bf16 = 4 VGPRs (MFMA operand)
typedef __attribute__((ext_vector_type(4))) float floatx4;  // MFMA accumulator

// ---- helpers ----------------------------------------------------------------
__device__ __forceinline__ u16 f2bf(float f) {            // f32 -> bf16, RNE
  u32 x = __float_as_uint(f);
  return (u16)((x + 0x7fffu + ((x >> 16) & 1u)) >> 16);
}

typedef __attribute__((address_space(1))) void gvoid;
typedef __attribute__((address_space(3))) void lvoid;
// async global->LDS, 16B/lane; LDS dest = wave-uniform base + lane*16 (m104)
__device__ __forceinline__ void cp16(const u16* g, u16* l) {
  __builtin_amdgcn_global_load_lds((gvoid*)g, (lvoid*)l, 16, 0, 0);
}

// ---- K1: dec_out f32 -> bf16, tiled [mt(8)][kt(16)][mi(128)][ki(32)] --------
// Also zeroes rowSum (block 0) so no separate memset dispatch is needed.
__global__ __launch_bounds__(256) void k_convA(const float* __restrict__ dec,
                                               u16* __restrict__ Ab,
                                               float* __restrict__ rowSum) {
  if (blockIdx.x == 0) {
    ((float4*)rowSum)[threadIdx.x] = (float4){0.f, 0.f, 0.f, 0.f};  // 1024 floats
  }
  int t = blockIdx.x * 256 + threadIdx.x;     // 65536 threads, 8 elems each
  int o = t * 8;
  int tile = o >> 12;                          // 4096 elems per tile
  int mt = tile >> 4, kt = tile & 15;
  int mi = (o & 4095) >> 5, ki = o & 31;       // ki in {0,8,16,24}
  const float* s = dec + (size_t)(mt * 128 + mi) * HDIM + kt * 32 + ki;
  float4 a = ((const float4*)s)[0];
  float4 b = ((const float4*)s)[1];
  union { u16 h[8]; uint4 v; } pk;
  pk.h[0] = f2bf(a.x); pk.h[1] = f2bf(a.y); pk.h[2] = f2bf(a.z); pk.h[3] = f2bf(a.w);
  pk.h[4] = f2bf(b.x); pk.h[5] = f2bf(b.y); pk.h[6] = f2bf(b.z); pk.h[7] = f2bf(b.w);
  *(uint4*)(Ab + o) = pk.v;
}

// ---- K2: W_gen f32 [k][n] -> bf16 tiled [nt(250)][kt(16)][ni(128)][ki(32)] --
// (transpose k<->n inner order via LDS; stride 36 breaks bank conflicts)
__global__ __launch_bounds__(256) void k_convW(const float* __restrict__ W,
                                               u16* __restrict__ Wb) {
  __shared__ u16 lds[128 * 36];
  int tileId = blockIdx.x;                 // 0..3999 = nt*16 + kt
  int nt = tileId >> 4, kt = tileId & 15;
  int t = threadIdx.x;
  const float* src = W + (size_t)kt * 32 * NV + (size_t)nt * 128;
#pragma unroll
  for (int i = 0; i < 4; ++i) {
    int f = t + 256 * i;                   // float4 id, 0..1023
    int kin = f >> 5, n4 = f & 31;         // coalesced float4 reads along n
    float4 v = *(const float4*)(src + (size_t)kin * NV + n4 * 4);
    int base = (n4 * 4) * 36 + kin;
    lds[base]       = f2bf(v.x);
    lds[base + 36]  = f2bf(v.y);
    lds[base + 72]  = f2bf(v.z);
    lds[base + 108] = f2bf(v.w);
  }
  __syncthreads();
  u16* dst = Wb + (size_t)tileId * 4096;
#pragma unroll
  for (int j = 0; j < 2; ++j) {
    int o = t * 8 + j * 2048;              // coalesced 16B writes
    int ni = o >> 5, ki0 = o & 31;
    const u16* p = &lds[ni * 36 + ki0];
    uint2 x = *(const uint2*)p;
    uint2 y = *(const uint2*)(p + 4);
    uint4 v; v.x = x.x; v.y = x.y; v.z = y.x; v.w = y.y;
    *(uint4*)(dst + o) = v;
  }
}

// ---- K3: src_hidden f32 -> bf16 tiled [b(8)][st(3)][kt(16)][si(128)][ki(32)]
// Direct retile (srch is [s][h] = [n][k], already k-contiguous). Rows with
// s >= 320 (padding of the 3rd tile) are zero-filled.
__global__ __launch_bounds__(256) void k_convS(const float* __restrict__ srch,
                                               u16* __restrict__ Sb) {
  int t = blockIdx.x * 256 + threadIdx.x;   // 196608 threads, 8 elems each
  int o = t * 8;
  int ki = o & 31;
  int ni = (o >> 5) & 127;
  int kt = (o >> 12) & 15;
  int r  = o >> 16;                          // b*3 + tile
  int tile = r % 3, b = r / 3;
  int s = tile * 128 + ni;
  uint4 v;
  if (s < LSRC) {
    const float* p = srch + ((size_t)b * LSRC + s) * HDIM + kt * 32 + ki;
    float4 a = ((const float4*)p)[0];
    float4 c = ((const float4*)p)[1];
    union { u16 h[8]; uint4 u; } pk;
    pk.h[0] = f2bf(a.x); pk.h[1] = f2bf(a.y); pk.h[2] = f2bf(a.z); pk.h[3] = f2bf(a.w);
    pk.h[4] = f2bf(c.x); pk.h[5] = f2bf(c.y); pk.h[6] = f2bf(c.z); pk.h[7] = f2bf(c.w);
    v = pk.u;
  } else {
    v = (uint4){0u, 0u, 0u, 0u};
  }
  *(uint4*)(Sb + o) = v;
}

// ---- K4: main GEMM 1024 x (32000 gen + 384 copy) x 512 bf16 MFMA ------------
// 128x128 tile, BK=32, 3-buffer LDS ring, prefetch distance 2, COUNTED vmcnt
// (never drained to 0 in the main loop - T3/T4). Raw s_barrier; per step:
//   lgkmcnt(0)  -> own ds_reads retired (buffer overwrite is race-free)
//   vmcnt(4)    -> own stage-loads for buf kt retired (kt+1's stay in flight)
//   s_barrier   -> all waves' quarter-stages of buf kt complete
//   stage kt+2 || ds_read kt || 16 MFMA
// Live buffers at step kt: {kt, kt+1, kt+2} mod 3 - all distinct.
// XCD swizzle: y = (bid>>6)*8 + (bid&7), x = (bid>>3)&7 puts all 8 m-blocks
// of one B-tile on one XCD (FETCH stays compulsory).
// y in [0,250): gen columns (Wb, +bias, bf16 exp -> wsE).
// y in {250,251,252}: copy-attention columns (Sb, masked, f32 exp -> wsCopy).
__global__ __launch_bounds__(256) void k_gemm(const u16* __restrict__ Ab,
                                              const u16* __restrict__ Wb,
                                              const u16* __restrict__ Sb,
                                              const float* __restrict__ bgen,
                                              const int* __restrict__ mask,
                                              u16* __restrict__ wsE,
                                              float* __restrict__ wsCopy,
                                              float* __restrict__ rowSum) {
  __shared__ u16 As[3][4096];   // [buf][mi*32+ki]  8 KiB each, 48 KiB total
  __shared__ u16 Bs[3][4096];   // [buf][ni*32+ki]
  int bid = blockIdx.x;
  int x = (bid >> 3) & 7;                  // m-tile (= batch b)
  int y = ((bid >> 6) << 3) | (bid & 7);   // n-tile, same-XCD grouping
  if (y >= 253) return;
  int t = threadIdx.x;
  int wid = t >> 6, lane = t & 63;
  int wm = wid >> 1, wn = wid & 1;         // 2x2 waves over 128x128 tile
  int quad = lane >> 4, l16 = lane & 15;

  const u16* At = Ab + (size_t)x * (16 * 4096);
  const u16* Bt = (y < 250) ? (Wb + (size_t)y * (16 * 4096))
                            : (Sb + (size_t)(x * 3 + (y - 250)) * (16 * 4096));
  // staging: each wave stages its own 2 KiB quarter of each A/B K-slab
  const u16* Ag0 = At + wid * 1024 + lane * 8;
  const u16* Bg0 = Bt + wid * 1024 + lane * 8;

  floatx4 acc[4][4];
#pragma unroll
  for (int i = 0; i < 4; ++i)
#pragma unroll
    for (int j = 0; j < 4; ++j) acc[i][j] = (floatx4){0.f, 0.f, 0.f, 0.f};

  // prologue: stage kt=0 and kt=1 into bufs 0,1 (8 VMEM instr in flight)
#pragma unroll
  for (int p = 0; p < 2; ++p) {
    const u16* ag = Ag0 + p * 4096;
    const u16* bg = Bg0 + p * 4096;
    cp16(ag,       &As[p][wid * 1024]);
    cp16(ag + 512, &As[p][wid * 1024 + 512]);
    cp16(bg,       &Bs[p][wid * 1024]);
    cp16(bg + 512, &Bs[p][wid * 1024 + 512]);
  }

#pragma unroll
  for (int kt = 0; kt < 16; ++kt) {
    const int cb = kt % 3;                  // compile-time (unrolled)
    // all of this wave's ds_reads (prev step) retired -> overwrite safe
    asm volatile("s_waitcnt lgkmcnt(0)" ::: "memory");
    // own loads for buf kt retired; buf kt+1's 4 loads may stay in flight
    if (kt < 15) asm volatile("s_waitcnt vmcnt(4)" ::: "memory");
    else         asm volatile("s_waitcnt vmcnt(0)" ::: "memory");
    __builtin_amdgcn_s_barrier();           // now ALL waves' buf-kt stages done
    asm volatile("" ::: "memory");          // no LDS access hoists above barrier
    if (kt < 14) {                          // stage kt+2 into buf (kt+2)%3
      const int sb = (kt + 2) % 3;
      const u16* ag = Ag0 + (kt + 2) * 4096;
      const u16* bg = Bg0 + (kt + 2) * 4096;
      cp16(ag,       &As[sb][wid * 1024]);
      cp16(ag + 512, &As[sb][wid * 1024 + 512]);
      cp16(bg,       &Bs[sb][wid * 1024]);
      cp16(bg + 512, &Bs[sb][wid * 1024 + 512]);
    }
    short8 aR[4], bR[4];
#pragma unroll
    for (int mt = 0; mt < 4; ++mt)
      aR[mt] = *(const short8*)&As[cb][(wm * 64 + mt * 16 + l16) * 32 + quad * 8];
#pragma unroll
    for (int nt = 0; nt < 4; ++nt)
      bR[nt] = *(const short8*)&Bs[cb][(wn * 64 + nt * 16 + l16) * 32 + quad * 8];
#pragma unroll
    for (int mt = 0; mt < 4; ++mt)
#pragma unroll
      for (int nt = 0; nt < 4; ++nt)
        acc[mt][nt] = __builtin_amdgcn_mfma_f32_16x16x32_bf16(aR[mt], bR[nt],
                                                              acc[mt][nt], 0, 0, 0);
  }

  int row0 = x * 128 + wm * 64;
  if (y < 250) {
    // gen epilogue: e = exp((acc + b) * H^-0.5); store bf16; reduce row sums
    int col0 = y * 128 + wn * 64;
    float bg[4];
#pragma unroll
    for (int nt = 0; nt < 4; ++nt) bg[nt] = bgen[col0 + nt * 16 + l16];
#pragma unroll
    for (int mt = 0; mt < 4; ++mt) {
      float rs[4] = {0.f, 0.f, 0.f, 0.f};
#pragma unroll
      for (int nt = 0; nt < 4; ++nt) {
        int col = col0 + nt * 16 + l16;
#pragma unroll
        for (int r = 0; r < 4; ++r) {
          int row = row0 + mt * 16 + quad * 4 + r;    // C/D layout (m89)
          float e = __expf((acc[mt][nt][r] + bg[nt]) * SCALEF);
          wsE[(size_t)row * NV + col] = f2bf(e);
          rs[r] += e;
        }
      }
#pragma unroll
      for (int r = 0; r < 4; ++r) {
        float v = rs[r];
        v += __shfl_xor(v, 1, 64);
        v += __shfl_xor(v, 2, 64);
        v += __shfl_xor(v, 4, 64);
        v += __shfl_xor(v, 8, 64);
        if (l16 == 0) atomicAdd(&rowSum[row0 + mt * 16 + quad * 4 + r], v);
      }
    }
  } else {
    // copy epilogue: e = mask ? exp(acc * H^-0.5) : 0; store f32 to wsCopy
    int b = x;
    int sBase = (y - 250) * 128 + wn * 64;
#pragma unroll
    for (int mt = 0; mt < 4; ++mt) {
      float rs[4] = {0.f, 0.f, 0.f, 0.f};
#pragma unroll
      for (int nt = 0; nt < 4; ++nt) {
        int s = sBase + nt * 16 + l16;
        int valid = (s < LSRC);
        int m = valid ? mask[b * LSRC + s] : 0;
#pragma unroll
        for (int r = 0; r < 4; ++r) {
          int row = row0 + mt * 16 + quad * 4 + r;
          float e = m ? __expf(acc[mt][nt][r] * SCALEF) : 0.f;
          if (valid) wsCopy[row * LSRC + s] = e;
          rs[r] += e;
        }
      }
#pragma unroll
      for (int r = 0; r < 4; ++r) {
        float v = rs[r];
        v += __shfl_xor(v, 1, 64);
        v += __shfl_xor(v, 2, 64);
        v += __shfl_xor(v, 4, 64);
        v += __shfl_xor(v, 8, 64);
        if (l16 == 0) atomicAdd(&rowSum[row0 + mt * 16 + quad * 4 + r], v);
      }
    }
  }
}

// ---- K5: normalize + scatter (one block owns one output row) ----------------
// Coalesced: each lane reads 8B (4 bf16) and writes one contiguous float4.
__global__ __launch_bounds__(256) void k_norm(const u16* __restrict__ wsE,
                                              const float* __restrict__ wsCopy,
                                              const float* __restrict__ rowSum,
                                              const int* __restrict__ context,
                                              const int* __restrict__ tp,
                                              const int* __restrict__ action,
                                              const int* __restrict__ loc2glo,
                                              float* __restrict__ out) {
  int r = blockIdx.x, b = r >> 7;
  float inv = 1.0f / rowSum[r];
  const uint2* src = (const uint2*)(wsE + (size_t)r * NV);
  float4* dst = (float4*)(out + (size_t)r * NV);
  for (int c = threadIdx.x; c < NV / 4; c += 256) {
    uint2 v = src[c];
    float4 o;
    o.x = __uint_as_float(v.x << 16) * inv;
    o.y = __uint_as_float(v.x & 0xffff0000u) * inv;
    o.z = __uint_as_float(v.y << 16) * inv;
    o.w = __uint_as_float(v.y & 0xffff0000u) * inv;
    dst[c] = o;
  }
  __syncthreads();   // drains stores (vmcnt) so atomics below see them at L2
  int t = threadIdx.x;
  float* op = out + (size_t)r * NV;
  atomicAdd(op + context[b * 256 + t], wsCopy[r * LSRC + t] * inv);
  if (t < 32) {
    atomicAdd(op + loc2glo[tp[b * 32 + t]],     wsCopy[r * LSRC + 256 + t] * inv);
    atomicAdd(op + loc2glo[action[b * 32 + t]], wsCopy[r * LSRC + 288 + t] * inv);
  }
}

// ---- launch -----------------------------------------------------------------
extern "C" void kernel_launch(void* const* d_in, const int* in_sizes, int n_in,
                              void* d_out, int out_size, void* d_ws, size_t ws_size,
                              hipStream_t stream) {
  const float* dec  = (const float*)d_in[0];
  const float* srch = (const float*)d_in[1];
  const float* Wg   = (const float*)d_in[2];
  const float* bg   = (const float*)d_in[3];
  const int*   mask = (const int*)d_in[4];
  const int*   ctx  = (const int*)d_in[5];
  const int*   tp   = (const int*)d_in[6];
  const int*   act  = (const int*)d_in[7];
  const int*   l2g  = (const int*)d_in[8];
  float* out = (float*)d_out;

  char* ws = (char*)d_ws;
  // ws layout (bytes):
  u16*   Wb      = (u16*)(ws);                    // 32,768,000  bf16 W tiled
  u16*   wsE     = (u16*)(ws + 32768000);         // 65,536,000  bf16 exp(gen)
  u16*   Ab      = (u16*)(ws + 98304000);         //  1,048,576  bf16 A tiled
  float* wsCopy  = (float*)(ws + 99352576);       //  1,310,720  fp32 exp(copy)
  float* rowSum  = (float*)(ws + 100663296);      //      4,096  fp32 row sums
  u16*   Sb      = (u16*)(ws + 100667392);        //  3,145,728  bf16 srch tiled

  hipLaunchKernelGGL(k_convA, dim3(256), dim3(256), 0, stream, dec, Ab, rowSum);
  hipLaunchKernelGGL(k_convW, dim3(4000), dim3(256), 0, stream, Wg, Wb);
  hipLaunchKernelGGL(k_convS, dim3(768), dim3(256), 0, stream, srch, Sb);
  hipLaunchKernelGGL(k_gemm, dim3(2048), dim3(256), 0, stream, Ab, Wb, Sb, bg, mask,
                     wsE, wsCopy, rowSum);
  hipLaunchKernelGGL(k_norm, dim3(MROWS), dim3(256), 0, stream, wsE, wsCopy, rowSum,
                     ctx, tp, act, l2g, out);
}

// Round 4
// 314.907 us; speedup vs baseline: 1.0999x; 1.0999x over previous
//
#include <hip/hip_runtime.h>
#include <stdint.h>
#include <stddef.h>

// Problem constants
#define NV    32000
#define HDIM  512
#define LSRC  320
#define MROWS 1024          // B * L_R
#define SCALEF 0.044194173824159216f   // 1/sqrt(512)

typedef unsigned short u16;
typedef unsigned int   u32;
typedef __attribute__((ext_vector_type(8))) short short8;   // 8 bf16 = 4 VGPRs (MFMA operand)
typedef __attribute__((ext_vector_type(4))) float floatx4;  // MFMA accumulator

// ---- helpers ----------------------------------------------------------------
__device__ __forceinline__ u16 f2bf(float f) {            // f32 -> bf16, RNE
  u32 x = __float_as_uint(f);
  return (u16)((x + 0x7fffu + ((x >> 16) & 1u)) >> 16);
}

typedef __attribute__((address_space(1))) void gvoid;
typedef __attribute__((address_space(3))) void lvoid;
// async global->LDS, 16B/lane; LDS dest = wave-uniform base + lane*16 (m104)
__device__ __forceinline__ void cp16(const u16* g, u16* l) {
  __builtin_amdgcn_global_load_lds((gvoid*)g, (lvoid*)l, 16, 0, 0);
}

// ---- K1: dec_out + src_hidden f32 -> bf16 retile (merged convA + convS) -----
// blocks [0,256):   dec -> Ab  [mt(8)][kt(16)][mi(128)][ki(32)]  (+ rowSum=0)
// blocks [256,1024): srch -> Sb [b(8)][st(3)][kt(16)][si(128)][ki(32)], s>=320 zero
__global__ __launch_bounds__(256) void k_conv(const float* __restrict__ dec,
                                              const float* __restrict__ srch,
                                              u16* __restrict__ Ab,
                                              u16* __restrict__ Sb,
                                              float* __restrict__ rowSum) {
  if (blockIdx.x < 256) {
    if (blockIdx.x == 0) {
      ((float4*)rowSum)[threadIdx.x] = (float4){0.f, 0.f, 0.f, 0.f};  // 1024 floats
    }
    int t = blockIdx.x * 256 + threadIdx.x;     // 65536 threads, 8 elems each
    int o = t * 8;
    int tile = o >> 12;                          // 4096 elems per tile
    int mt = tile >> 4, kt = tile & 15;
    int mi = (o & 4095) >> 5, ki = o & 31;
    const float* s = dec + (size_t)(mt * 128 + mi) * HDIM + kt * 32 + ki;
    float4 a = ((const float4*)s)[0];
    float4 b = ((const float4*)s)[1];
    union { u16 h[8]; uint4 v; } pk;
    pk.h[0] = f2bf(a.x); pk.h[1] = f2bf(a.y); pk.h[2] = f2bf(a.z); pk.h[3] = f2bf(a.w);
    pk.h[4] = f2bf(b.x); pk.h[5] = f2bf(b.y); pk.h[6] = f2bf(b.z); pk.h[7] = f2bf(b.w);
    *(uint4*)(Ab + o) = pk.v;
  } else {
    int t = (blockIdx.x - 256) * 256 + threadIdx.x;   // 196608 threads, 8 elems
    int o = t * 8;
    int ki = o & 31;
    int ni = (o >> 5) & 127;
    int kt = (o >> 12) & 15;
    int r  = o >> 16;                          // b*3 + tile
    int tile = r % 3, b = r / 3;
    int s = tile * 128 + ni;
    uint4 v;
    if (s < LSRC) {
      const float* p = srch + ((size_t)b * LSRC + s) * HDIM + kt * 32 + ki;
      float4 a = ((const float4*)p)[0];
      float4 c = ((const float4*)p)[1];
      union { u16 h[8]; uint4 u; } pk;
      pk.h[0] = f2bf(a.x); pk.h[1] = f2bf(a.y); pk.h[2] = f2bf(a.z); pk.h[3] = f2bf(a.w);
      pk.h[4] = f2bf(c.x); pk.h[5] = f2bf(c.y); pk.h[6] = f2bf(c.z); pk.h[7] = f2bf(c.w);
      v = pk.u;
    } else {
      v = (uint4){0u, 0u, 0u, 0u};
    }
    *(uint4*)(Sb + o) = v;
  }
}

// ---- K2: W_gen f32 [k][n] -> bf16 tiled [nt(250)][kt(16)][ni(128)][ki(32)] --
// (transpose k<->n inner order via LDS; stride 36 breaks bank conflicts)
__global__ __launch_bounds__(256) void k_convW(const float* __restrict__ W,
                                               u16* __restrict__ Wb) {
  __shared__ u16 lds[128 * 36];
  int tileId = blockIdx.x;                 // 0..3999 = nt*16 + kt
  int nt = tileId >> 4, kt = tileId & 15;
  int t = threadIdx.x;
  const float* src = W + (size_t)kt * 32 * NV + (size_t)nt * 128;
#pragma unroll
  for (int i = 0; i < 4; ++i) {
    int f = t + 256 * i;                   // float4 id, 0..1023
    int kin = f >> 5, n4 = f & 31;         // coalesced float4 reads along n
    float4 v = *(const float4*)(src + (size_t)kin * NV + n4 * 4);
    int base = (n4 * 4) * 36 + kin;
    lds[base]       = f2bf(v.x);
    lds[base + 36]  = f2bf(v.y);
    lds[base + 72]  = f2bf(v.z);
    lds[base + 108] = f2bf(v.w);
  }
  __syncthreads();
  u16* dst = Wb + (size_t)tileId * 4096;
#pragma unroll
  for (int j = 0; j < 2; ++j) {
    int o = t * 8 + j * 2048;              // coalesced 16B writes
    int ni = o >> 5, ki0 = o & 31;
    const u16* p = &lds[ni * 36 + ki0];
    uint2 x = *(const uint2*)p;
    uint2 y = *(const uint2*)(p + 4);
    uint4 v; v.x = x.x; v.y = x.y; v.z = y.x; v.w = y.y;
    *(uint4*)(dst + o) = v;
  }
}

// ---- K4: main GEMM 1024 x (32000 gen + 384 copy) x 512 bf16 MFMA ------------
// 128x128 tile, BK=32, 3-buffer LDS ring, prefetch distance 2, counted vmcnt.
// OPERANDS SWAPPED: acc = mfma(B, A) -> D transposed: each thread holds
// row m = l16 (lane-local) and 4 CONSECUTIVE cols n = quad*4+r. Epilogue:
// packed uint2/float4 stores, 2-shuffle row reduce (was 64 scalar stores + 64
// shuffles). Main-loop fragments unchanged.
// XCD swizzle: y = (bid>>6)*8 + (bid&7), x = (bid>>3)&7.
// y in [0,250): gen columns (Wb, +bias, bf16 exp -> wsE).
// y in {250,251,252}: copy columns (Sb, masked, f32 exp -> wsCopy).
__global__ __launch_bounds__(256) void k_gemm(const u16* __restrict__ Ab,
                                              const u16* __restrict__ Wb,
                                              const u16* __restrict__ Sb,
                                              const float* __restrict__ bgen,
                                              const int* __restrict__ mask,
                                              u16* __restrict__ wsE,
                                              float* __restrict__ wsCopy,
                                              float* __restrict__ rowSum) {
  __shared__ u16 As[3][4096];   // [buf][mi*32+ki]  8 KiB each, 48 KiB total
  __shared__ u16 Bs[3][4096];   // [buf][ni*32+ki]
  int bid = blockIdx.x;
  int x = (bid >> 3) & 7;                  // m-tile (= batch b)
  int y = ((bid >> 6) << 3) | (bid & 7);   // n-tile, same-XCD grouping
  if (y >= 253) return;
  int t = threadIdx.x;
  int wid = t >> 6, lane = t & 63;
  int wm = wid >> 1, wn = wid & 1;         // 2x2 waves over 128x128 tile
  int quad = lane >> 4, l16 = lane & 15;

  const u16* At = Ab + (size_t)x * (16 * 4096);
  const u16* Bt = (y < 250) ? (Wb + (size_t)y * (16 * 4096))
                            : (Sb + (size_t)(x * 3 + (y - 250)) * (16 * 4096));
  // staging: each wave stages its own 2 KiB quarter of each A/B K-slab
  const u16* Ag0 = At + wid * 1024 + lane * 8;
  const u16* Bg0 = Bt + wid * 1024 + lane * 8;

  floatx4 acc[4][4];
#pragma unroll
  for (int i = 0; i < 4; ++i)
#pragma unroll
    for (int j = 0; j < 4; ++j) acc[i][j] = (floatx4){0.f, 0.f, 0.f, 0.f};

  // prologue: stage kt=0 and kt=1 into bufs 0,1 (8 VMEM instr in flight)
#pragma unroll
  for (int p = 0; p < 2; ++p) {
    const u16* ag = Ag0 + p * 4096;
    const u16* bg = Bg0 + p * 4096;
    cp16(ag,       &As[p][wid * 1024]);
    cp16(ag + 512, &As[p][wid * 1024 + 512]);
    cp16(bg,       &Bs[p][wid * 1024]);
    cp16(bg + 512, &Bs[p][wid * 1024 + 512]);
  }

#pragma unroll
  for (int kt = 0; kt < 16; ++kt) {
    const int cb = kt % 3;                  // compile-time (unrolled)
    // all of this wave's ds_reads (prev step) retired -> overwrite safe
    asm volatile("s_waitcnt lgkmcnt(0)" ::: "memory");
    // own loads for buf kt retired; buf kt+1's 4 loads may stay in flight
    if (kt < 15) asm volatile("s_waitcnt vmcnt(4)" ::: "memory");
    else         asm volatile("s_waitcnt vmcnt(0)" ::: "memory");
    __builtin_amdgcn_s_barrier();           // now ALL waves' buf-kt stages done
    asm volatile("" ::: "memory");          // no LDS access hoists above barrier
    if (kt < 14) {                          // stage kt+2 into buf (kt+2)%3
      const int sb = (kt + 2) % 3;
      const u16* ag = Ag0 + (kt + 2) * 4096;
      const u16* bg = Bg0 + (kt + 2) * 4096;
      cp16(ag,       &As[sb][wid * 1024]);
      cp16(ag + 512, &As[sb][wid * 1024 + 512]);
      cp16(bg,       &Bs[sb][wid * 1024]);
      cp16(bg + 512, &Bs[sb][wid * 1024 + 512]);
    }
    short8 aR[4], bR[4];
#pragma unroll
    for (int mt = 0; mt < 4; ++mt)
      aR[mt] = *(const short8*)&As[cb][(wm * 64 + mt * 16 + l16) * 32 + quad * 8];
#pragma unroll
    for (int nt = 0; nt < 4; ++nt)
      bR[nt] = *(const short8*)&Bs[cb][(wn * 64 + nt * 16 + l16) * 32 + quad * 8];
    __builtin_amdgcn_s_setprio(1);
#pragma unroll
    for (int mt = 0; mt < 4; ++mt)
#pragma unroll
      for (int nt = 0; nt < 4; ++nt)
        acc[mt][nt] = __builtin_amdgcn_mfma_f32_16x16x32_bf16(bR[nt], aR[mt],
                                                              acc[mt][nt], 0, 0, 0);
    __builtin_amdgcn_s_setprio(0);
  }

  // Swapped-D layout: for acc[mt][nt], thread holds
  //   row m = row0 + mt*16 + l16          (lane-local, fixed)
  //   cols n = ncol0 + nt*16 + quad*4 + r (4 consecutive, r = reg)
  int row0 = x * 128 + wm * 64;
  if (y < 250) {
    int col0 = y * 128 + wn * 64;
    float bq[4][4];                        // bias*SCALEF, [nt][r], quad-broadcast
#pragma unroll
    for (int nt = 0; nt < 4; ++nt) {
      float4 v = *(const float4*)(bgen + col0 + nt * 16 + quad * 4);
      bq[nt][0] = v.x * SCALEF; bq[nt][1] = v.y * SCALEF;
      bq[nt][2] = v.z * SCALEF; bq[nt][3] = v.w * SCALEF;
    }
#pragma unroll
    for (int mt = 0; mt < 4; ++mt) {
      int row = row0 + mt * 16 + l16;
      float rsum = 0.f;
#pragma unroll
      for (int nt = 0; nt < 4; ++nt) {
        float e0 = __expf(fmaf(acc[mt][nt][0], SCALEF, bq[nt][0]));
        float e1 = __expf(fmaf(acc[mt][nt][1], SCALEF, bq[nt][1]));
        float e2 = __expf(fmaf(acc[mt][nt][2], SCALEF, bq[nt][2]));
        float e3 = __expf(fmaf(acc[mt][nt][3], SCALEF, bq[nt][3]));
        uint2 pk;
        pk.x = (u32)f2bf(e0) | ((u32)f2bf(e1) << 16);
        pk.y = (u32)f2bf(e2) | ((u32)f2bf(e3) << 16);
        *(uint2*)(wsE + (size_t)row * NV + col0 + nt * 16 + quad * 4) = pk;
        rsum += (e0 + e1) + (e2 + e3);
      }
      rsum += __shfl_xor(rsum, 16, 64);
      rsum += __shfl_xor(rsum, 32, 64);
      if (lane < 16) atomicAdd(&rowSum[row], rsum);
    }
  } else {
    int b = x;
    int sBase = (y - 250) * 128 + wn * 64;
    if (sBase < LSRC) {                    // wave-uniform; sBase=320 is all-pad
      int mq[4][4];                        // mask, [nt][r], quad-broadcast
#pragma unroll
      for (int nt = 0; nt < 4; ++nt) {
        int4 v = *(const int4*)(mask + b * LSRC + sBase + nt * 16 + quad * 4);
        mq[nt][0] = v.x; mq[nt][1] = v.y; mq[nt][2] = v.z; mq[nt][3] = v.w;
      }
#pragma unroll
      for (int mt = 0; mt < 4; ++mt) {
        int row = row0 + mt * 16 + l16;
        float rsum = 0.f;
#pragma unroll
        for (int nt = 0; nt < 4; ++nt) {
          float4 ev;
          ev.x = mq[nt][0] ? __expf(acc[mt][nt][0] * SCALEF) : 0.f;
          ev.y = mq[nt][1] ? __expf(acc[mt][nt][1] * SCALEF) : 0.f;
          ev.z = mq[nt][2] ? __expf(acc[mt][nt][2] * SCALEF) : 0.f;
          ev.w = mq[nt][3] ? __expf(acc[mt][nt][3] * SCALEF) : 0.f;
          *(float4*)(wsCopy + (size_t)row * LSRC + sBase + nt * 16 + quad * 4) = ev;
          rsum += (ev.x + ev.y) + (ev.z + ev.w);
        }
        rsum += __shfl_xor(rsum, 16, 64);
        rsum += __shfl_xor(rsum, 32, 64);
        if (lane < 16) atomicAdd(&rowSum[row], rsum);
      }
    }
  }
}

// ---- K5: normalize + scatter (one block owns one output row, 512 thr) -------
__global__ __launch_bounds__(512) void k_norm(const u16* __restrict__ wsE,
                                              const float* __restrict__ wsCopy,
                                              const float* __restrict__ rowSum,
                                              const int* __restrict__ context,
                                              const int* __restrict__ tp,
                                              const int* __restrict__ action,
                                              const int* __restrict__ loc2glo,
                                              float* __restrict__ out) {
  int r = blockIdx.x, b = r >> 7;
  float inv = 1.0f / rowSum[r];
  const uint2* src = (const uint2*)(wsE + (size_t)r * NV);
  float4* dst = (float4*)(out + (size_t)r * NV);
  for (int c = threadIdx.x; c < NV / 4; c += 512) {
    uint2 v = src[c];
    float4 o;
    o.x = __uint_as_float(v.x << 16) * inv;
    o.y = __uint_as_float(v.x & 0xffff0000u) * inv;
    o.z = __uint_as_float(v.y << 16) * inv;
    o.w = __uint_as_float(v.y & 0xffff0000u) * inv;
    dst[c] = o;
  }
  __syncthreads();   // drains stores (vmcnt) so atomics below see them at L2
  int t = threadIdx.x;
  float* op = out + (size_t)r * NV;
  if (t < 256) {
    atomicAdd(op + context[b * 256 + t], wsCopy[r * LSRC + t] * inv);
  } else if (t < 288) {
    int i = t - 256;
    atomicAdd(op + loc2glo[tp[b * 32 + i]], wsCopy[r * LSRC + 256 + i] * inv);
  } else if (t < 320) {
    int i = t - 288;
    atomicAdd(op + loc2glo[action[b * 32 + i]], wsCopy[r * LSRC + 288 + i] * inv);
  }
}

// ---- launch -----------------------------------------------------------------
extern "C" void kernel_launch(void* const* d_in, const int* in_sizes, int n_in,
                              void* d_out, int out_size, void* d_ws, size_t ws_size,
                              hipStream_t stream) {
  const float* dec  = (const float*)d_in[0];
  const float* srch = (const float*)d_in[1];
  const float* Wg   = (const float*)d_in[2];
  const float* bg   = (const float*)d_in[3];
  const int*   mask = (const int*)d_in[4];
  const int*   ctx  = (const int*)d_in[5];
  const int*   tp   = (const int*)d_in[6];
  const int*   act  = (const int*)d_in[7];
  const int*   l2g  = (const int*)d_in[8];
  float* out = (float*)d_out;

  char* ws = (char*)d_ws;
  // ws layout (bytes):
  u16*   Wb      = (u16*)(ws);                    // 32,768,000  bf16 W tiled
  u16*   wsE     = (u16*)(ws + 32768000);         // 65,536,000  bf16 exp(gen)
  u16*   Ab      = (u16*)(ws + 98304000);         //  1,048,576  bf16 A tiled
  float* wsCopy  = (float*)(ws + 99352576);       //  1,310,720  fp32 exp(copy)
  float* rowSum  = (float*)(ws + 100663296);      //      4,096  fp32 row sums
  u16*   Sb      = (u16*)(ws + 100667392);        //  3,145,728  bf16 srch tiled

  hipLaunchKernelGGL(k_conv, dim3(1024), dim3(256), 0, stream, dec, srch, Ab, Sb, rowSum);
  hipLaunchKernelGGL(k_convW, dim3(4000), dim3(256), 0, stream, Wg, Wb);
  hipLaunchKernelGGL(k_gemm, dim3(2048), dim3(256), 0, stream, Ab, Wb, Sb, bg, mask,
                     wsE, wsCopy, rowSum);
  hipLaunchKernelGGL(k_norm, dim3(MROWS), dim3(512), 0, stream, wsE, wsCopy, rowSum,
                     ctx, tp, act, l2g, out);
}